// Round 6
// baseline (458.062 us; speedup 1.0000x reference)
//
#include <hip/hip_runtime.h>

#define EPSF 1e-8f
#define DD 128   // feature dim, fixed by problem

struct V2 { float4 A, B; };

// ---------- small helpers ----------
__device__ __forceinline__ float4 ld4(const float* p){ return *reinterpret_cast<const float4*>(p); }
__device__ __forceinline__ void st4(float* p, const float4& v){ *reinterpret_cast<float4*>(p) = v; }
__device__ __forceinline__ float dot4(const float4& a, const float4& b){
  return a.x*b.x + a.y*b.y + a.z*b.z + a.w*b.w;
}
__device__ __forceinline__ void fma4(float4& acc, const float4& a, float s){
  acc.x += a.x*s; acc.y += a.y*s; acc.z += a.z*s; acc.w += a.w*s;
}
__device__ __forceinline__ float4 mix4(float a, const float4& v, const float4& x){
  float4 r;
  r.x = (1.f-a)*v.x + a*x.x;
  r.y = (1.f-a)*v.y + a*x.y;
  r.z = (1.f-a)*v.z + a*x.z;
  r.w = (1.f-a)*v.w + a*x.w;
  return r;
}
__device__ __forceinline__ float red16(float v){
  v += __shfl_xor(v, 1);
  v += __shfl_xor(v, 2);
  v += __shfl_xor(v, 4);
  v += __shfl_xor(v, 8);
  return v;
}
__device__ __forceinline__ V2 ldrow(const float* p, size_t base, int l){
  V2 v; v.A = ld4(p + base + l*4); v.B = ld4(p + base + 64 + l*4); return v;
}
__device__ __forceinline__ float dotV(const V2& a, const V2& b){
  return dot4(a.A, b.A) + dot4(a.B, b.B);
}
// block-level reduction of 16 row-groups' (2x float4 per lane) partials into dst[0..127]
__device__ __forceinline__ void block_red16(float* red, int g, int l, int t,
                                            const V2& acc, float* dst){
  red[g*DD + l*4+0] = acc.A.x;
  red[g*DD + l*4+1] = acc.A.y;
  red[g*DD + l*4+2] = acc.A.z;
  red[g*DD + l*4+3] = acc.A.w;
  red[g*DD + 64 + l*4+0] = acc.B.x;
  red[g*DD + 64 + l*4+1] = acc.B.y;
  red[g*DD + 64 + l*4+2] = acc.B.z;
  red[g*DD + 64 + l*4+3] = acc.B.w;
  __syncthreads();
  if (t < DD){
    float s = 0.f;
    #pragma unroll
    for (int q = 0; q < 16; ++q) s += red[q*DD + t];
    dst[t] = s;
  }
  __syncthreads();
}

// producer-side finalize: last block per batch reduces partials -> vecs[vg0..vg0+nv)
// (canonical threadFenceReduction pattern; sum order c=0..CH-1, bit-identical to old kFin)
__device__ __forceinline__ void finalize(const float* __restrict__ part,
                                         float* __restrict__ vecs,
                                         unsigned* __restrict__ cnt,
                                         int B, int b, int CH, int nv, int vg0, int t){
  __shared__ int lastf;
  __threadfence();
  if (t == 0) lastf = (atomicAdd(&cnt[b], 1u) == (unsigned)(CH - 1)) ? 1 : 0;
  __syncthreads();
  if (!lastf) return;
  __threadfence();
  for (int i = t; i < nv*DD; i += 256){
    int v = i >> 7, d = i & (DD-1);
    const float* p = part + ((size_t)(v*B + b)*CH)*DD + d;
    float s = 0.f;
    #pragma unroll 8
    for (int c = 0; c < CH; ++c) s += p[(size_t)c*DD];
    vecs[((size_t)((vg0 + v)*B + b))*DD + d] = s;
  }
}

// ---------- per-row bodies ----------
__device__ __forceinline__ void ka_row(const V2& a, const V2& c1, const V2& c2,
                                       const V2& atv, float nat, int l,
                                       float* __restrict__ f2cn, size_t idx,
                                       V2& accF, V2& accA){
  float dp = red16(dotV(atv, a));
  float n2 = red16(dotV(a, a));
  float na = sqrtf(n2);
  float cs = dp / fmaxf(nat * na, EPSF);
  if (l == 0) *reinterpret_cast<float2*>(f2cn + 2*idx) = make_float2(cs, na);
  fma4(accF.A, c1.A, cs); fma4(accF.B, c1.B, cs);
  fma4(accA.A, c2.A, cs); fma4(accA.B, c2.B, cs);
}

__device__ __forceinline__ void kb_row(const V2& a, const V2& t4, const V2& c1, const V2& c2,
                                       const V2& fn, const V2& ag, float nfn, float nag,
                                       float na, int l, float* __restrict__ csfn, size_t idx,
                                       V2& accP, V2& accB, V2& accT, V2& accL, V2& accR){
  float dfn = red16(dotV(fn, a));
  float dag = red16(dotV(ag, a));
  float cf = dfn / fmaxf(nfn*na, EPSF);
  float ca = dag / fmaxf(nag*na, EPSF);
  if (l == 0) csfn[idx] = cf;
  fma4(accP.A, c1.A, cf); fma4(accP.B, c1.B, cf);
  fma4(accB.A, c2.A, cf); fma4(accB.B, c2.B, cf);
  fma4(accT.A, t4.A, ca); fma4(accT.B, t4.B, ca);
  fma4(accL.A, c1.A, ca); fma4(accL.B, c1.B, ca);
  fma4(accR.A, c2.A, ca); fma4(accR.B, c2.B, ca);
}

__device__ __forceinline__ void kc_row(const V2& a, const V2& t4, const V2& c1, const V2& c2,
                                       const V2& ag, const V2& pm, const V2& bd,
                                       const V2& xt, const V2& xl, const V2& xr,
                                       float npm, float nbd, float na, int l,
                                       float* __restrict__ sc4, size_t idx,
                                       V2& accT, V2& accL, V2& accR){
  float dp = red16(dotV(pm, a));
  float db = red16(dotV(bd, a));
  float csp = dp / fmaxf(npm*na, EPSF);
  float ap  = csp > EPSF ? csp : 0.f;
  float csb = db / fmaxf(nbd*na, EPSF);
  V2 tn { mix4(ap, t4.A, xt.A), mix4(ap, t4.B, xt.B) };
  V2 c1n{ mix4(ap, c1.A, xl.A), mix4(ap, c1.B, xl.B) };
  V2 c2n{ mix4(ap, c2.A, xr.A), mix4(ap, c2.B, xr.B) };
  float d1  = red16(dotV(pm, c1n));
  float n21 = red16(dotV(c1n, c1n));
  float d2  = red16(dotV(pm, c2n));
  float n22 = red16(dotV(c2n, c2n));
  float s1 = d1 / fmaxf(npm * sqrtf(n21), EPSF);
  float s2 = d2 / fmaxf(npm * sqrtf(n22), EPSF);
  V2 c1f{ mix4(s1, c1n.A, ag.A), mix4(s1, c1n.B, ag.B) };
  V2 c2f{ mix4(s2, c2n.A, ag.A), mix4(s2, c2n.B, ag.B) };
  if (l == 0) *reinterpret_cast<float4*>(sc4 + 4*idx) = make_float4(ap, csb, s1, s2);
  fma4(accT.A, tn.A,  csb); fma4(accT.B, tn.B,  csb);
  fma4(accL.A, c1f.A, csb); fma4(accL.B, c1f.B, csb);
  fma4(accR.A, c2f.A, csb); fma4(accR.B, c2f.B, csb);
}

// ---------- kernel A ----------
__global__ __launch_bounds__(256) void kA(const float* __restrict__ at,
                                          const float* __restrict__ addr,
                                          const float* __restrict__ col1,
                                          const float* __restrict__ col2,
                                          float* __restrict__ f2cn,
                                          float* __restrict__ vecs,
                                          float* __restrict__ partA,
                                          unsigned* __restrict__ cntA,
                                          int B, int N, int CH){
  __shared__ float red[16*DD];
  int blk = blockIdx.x, b = blk / CH, c = blk % CH;
  int rows = N / CH, n0 = c * rows;
  int t = threadIdx.x, g = t >> 4, l = t & 15;
  size_t bN = (size_t)b * N;

  const float* atp = at + (size_t)b*DD;
  V2 atv{ ld4(atp + l*4), ld4(atp + 64 + l*4) };
  float nat = sqrtf(red16(dotV(atv, atv)));

  V2 zz{ make_float4(0,0,0,0), make_float4(0,0,0,0) };
  V2 accF = zz, accA = zz;
  int r = g;
  #pragma unroll 1
  for (; r + 16 < rows; r += 32){
    size_t n1 = (size_t)n0 + r, n2 = (size_t)n0 + r + 16;
    size_t b1 = (bN + n1)*DD, b2 = (bN + n2)*DD;
    V2 a1 = ldrow(addr, b1, l), a2 = ldrow(addr, b2, l);
    V2 x1 = ldrow(col1, b1, l), x2 = ldrow(col1, b2, l);
    V2 y1 = ldrow(col2, b1, l), y2 = ldrow(col2, b2, l);
    ka_row(a1, x1, y1, atv, nat, l, f2cn, bN + n1, accF, accA);
    ka_row(a2, x2, y2, atv, nat, l, f2cn, bN + n2, accF, accA);
  }
  if (r < rows){
    size_t n1 = (size_t)n0 + r, b1 = (bN + n1)*DD;
    V2 a1 = ldrow(addr, b1, l), x1 = ldrow(col1, b1, l), y1 = ldrow(col2, b1, l);
    ka_row(a1, x1, y1, atv, nat, l, f2cn, bN + n1, accF, accA);
  }
  block_red16(red, g, l, t, accF, partA + ((size_t)(0*B + b)*CH + c)*DD);
  block_red16(red, g, l, t, accA, partA + ((size_t)(1*B + b)*CH + c)*DD);
  finalize(partA, vecs, cntA, B, b, CH, 2, 0, t);
}

// ---------- kernel B ----------
__global__ __launch_bounds__(256) void kB(const float* __restrict__ addr,
                                          const float* __restrict__ tags,
                                          const float* __restrict__ col1,
                                          const float* __restrict__ col2,
                                          const float* __restrict__ f2cn,
                                          float* __restrict__ csfn,
                                          float* __restrict__ vecs,
                                          float* __restrict__ partB,
                                          unsigned* __restrict__ cntB,
                                          int B, int N, int CH){
  __shared__ float red[16*DD];
  int blk = blockIdx.x, b = blk / CH, c = blk % CH;
  int rows = N / CH, n0 = c * rows;
  int t = threadIdx.x, g = t >> 4, l = t & 15;
  size_t bN = (size_t)b * N;
  size_t BDv = (size_t)B * DD;

  const float* fnp = vecs + (size_t)b*DD;
  const float* agp = vecs + BDv + (size_t)b*DD;
  V2 fn{ ld4(fnp + l*4), ld4(fnp + 64 + l*4) };
  V2 ag{ ld4(agp + l*4), ld4(agp + 64 + l*4) };
  float nfn = sqrtf(red16(dotV(fn, fn)));
  float nag = sqrtf(red16(dotV(ag, ag)));

  V2 zz{ make_float4(0,0,0,0), make_float4(0,0,0,0) };
  V2 accP = zz, accB = zz, accT = zz, accL = zz, accR = zz;
  int r = g;
  #pragma unroll 1
  for (; r + 16 < rows; r += 32){
    size_t n1 = (size_t)n0 + r, n2 = (size_t)n0 + r + 16;
    size_t b1 = (bN + n1)*DD, b2 = (bN + n2)*DD;
    V2 a1 = ldrow(addr, b1, l), a2 = ldrow(addr, b2, l);
    V2 t1 = ldrow(tags, b1, l), t2 = ldrow(tags, b2, l);
    V2 x1 = ldrow(col1, b1, l), x2 = ldrow(col1, b2, l);
    V2 y1 = ldrow(col2, b1, l), y2 = ldrow(col2, b2, l);
    float na1 = f2cn[2*(bN + n1) + 1], na2 = f2cn[2*(bN + n2) + 1];
    kb_row(a1, t1, x1, y1, fn, ag, nfn, nag, na1, l, csfn, bN + n1, accP, accB, accT, accL, accR);
    kb_row(a2, t2, x2, y2, fn, ag, nfn, nag, na2, l, csfn, bN + n2, accP, accB, accT, accL, accR);
  }
  if (r < rows){
    size_t n1 = (size_t)n0 + r, b1 = (bN + n1)*DD;
    V2 a1 = ldrow(addr, b1, l), t1 = ldrow(tags, b1, l);
    V2 x1 = ldrow(col1, b1, l), y1 = ldrow(col2, b1, l);
    float na1 = f2cn[2*(bN + n1) + 1];
    kb_row(a1, t1, x1, y1, fn, ag, nfn, nag, na1, l, csfn, bN + n1, accP, accB, accT, accL, accR);
  }
  block_red16(red, g, l, t, accP, partB + ((size_t)(0*B + b)*CH + c)*DD);
  block_red16(red, g, l, t, accB, partB + ((size_t)(1*B + b)*CH + c)*DD);
  block_red16(red, g, l, t, accT, partB + ((size_t)(2*B + b)*CH + c)*DD);
  block_red16(red, g, l, t, accL, partB + ((size_t)(3*B + b)*CH + c)*DD);
  block_red16(red, g, l, t, accR, partB + ((size_t)(4*B + b)*CH + c)*DD);
  finalize(partB, vecs, cntB, B, b, CH, 5, 2, t);
}

// ---------- kernel C ----------
__global__ __launch_bounds__(256) void kC(const float* __restrict__ addr,
                                          const float* __restrict__ tags,
                                          const float* __restrict__ col1,
                                          const float* __restrict__ col2,
                                          const float* __restrict__ f2cn,
                                          float* __restrict__ sc4,
                                          float* __restrict__ vecs,
                                          float* __restrict__ partC,
                                          unsigned* __restrict__ cntC,
                                          int B, int N, int CH){
  __shared__ float red[16*DD];
  int blk = blockIdx.x, b = blk / CH, c = blk % CH;
  int rows = N / CH, n0 = c * rows;
  int t = threadIdx.x, g = t >> 4, l = t & 15;
  size_t bN = (size_t)b * N;
  size_t BDv = (size_t)B * DD;

  const float* vp = vecs + (size_t)b*DD;
  V2 ag{ ld4(vp + 1*BDv + l*4), ld4(vp + 1*BDv + 64 + l*4) };
  V2 pm{ ld4(vp + 2*BDv + l*4), ld4(vp + 2*BDv + 64 + l*4) };
  V2 bd{ ld4(vp + 3*BDv + l*4), ld4(vp + 3*BDv + 64 + l*4) };
  V2 xt{ ld4(vp + 4*BDv + l*4), ld4(vp + 4*BDv + 64 + l*4) };
  V2 xl{ ld4(vp + 5*BDv + l*4), ld4(vp + 5*BDv + 64 + l*4) };
  V2 xr{ ld4(vp + 6*BDv + l*4), ld4(vp + 6*BDv + 64 + l*4) };
  float npm = sqrtf(red16(dotV(pm, pm)));
  float nbd = sqrtf(red16(dotV(bd, bd)));

  V2 zz{ make_float4(0,0,0,0), make_float4(0,0,0,0) };
  V2 accT = zz, accL = zz, accR = zz;
  int r = g;
  #pragma unroll 1
  for (; r + 16 < rows; r += 32){
    size_t n1 = (size_t)n0 + r, n2 = (size_t)n0 + r + 16;
    size_t b1 = (bN + n1)*DD, b2 = (bN + n2)*DD;
    V2 a1 = ldrow(addr, b1, l), a2 = ldrow(addr, b2, l);
    V2 t1 = ldrow(tags, b1, l), t2 = ldrow(tags, b2, l);
    V2 x1 = ldrow(col1, b1, l), x2 = ldrow(col1, b2, l);
    V2 y1 = ldrow(col2, b1, l), y2 = ldrow(col2, b2, l);
    float na1 = f2cn[2*(bN + n1) + 1], na2 = f2cn[2*(bN + n2) + 1];
    kc_row(a1, t1, x1, y1, ag, pm, bd, xt, xl, xr, npm, nbd, na1, l, sc4, bN + n1, accT, accL, accR);
    kc_row(a2, t2, x2, y2, ag, pm, bd, xt, xl, xr, npm, nbd, na2, l, sc4, bN + n2, accT, accL, accR);
  }
  if (r < rows){
    size_t n1 = (size_t)n0 + r, b1 = (bN + n1)*DD;
    V2 a1 = ldrow(addr, b1, l), t1 = ldrow(tags, b1, l);
    V2 x1 = ldrow(col1, b1, l), y1 = ldrow(col2, b1, l);
    float na1 = f2cn[2*(bN + n1) + 1];
    kc_row(a1, t1, x1, y1, ag, pm, bd, xt, xl, xr, npm, nbd, na1, l, sc4, bN + n1, accT, accL, accR);
  }
  block_red16(red, g, l, t, accT, partC + ((size_t)(0*B + b)*CH + c)*DD);
  block_red16(red, g, l, t, accL, partC + ((size_t)(1*B + b)*CH + c)*DD);
  block_red16(red, g, l, t, accR, partC + ((size_t)(2*B + b)*CH + c)*DD);
  finalize(partC, vecs, cntC, B, b, CH, 3, 7, t);
}

// ---------- kernel E: streaming final pass ----------
__device__ __forceinline__ void ke_row(size_t bn, int l2, int gcn,
    const float* __restrict__ tags, const float* __restrict__ col1, const float* __restrict__ col2,
    const float* __restrict__ f2cn, const float* __restrict__ csfn, const float* __restrict__ sc4,
    const float4& ag, const float4& xt, const float4& xl, const float4& xr,
    const float4& bt, const float4& bl, const float4& br, const float4& z4,
    float* __restrict__ o_t, float* __restrict__ o_1, float* __restrict__ o_2){
  float4 sc = ld4(sc4 + 4*bn);                                   // ap, csb, s1, s2
  float2 cn = *reinterpret_cast<const float2*>(f2cn + 2*bn);     // cs0, na
  float cf = csfn[bn];
  float ap = sc.x, cb = sc.y, s1 = sc.z, s2 = sc.w, c0 = cn.x;
  float aat = c0 > EPSF ? c0 : 0.f;
  float af  = cf > EPSF ? cf : 0.f;
  float ab  = cb > EPSF ? cb : 0.f;
  float q = (1.f-af)*(1.f-ap)*(1.f-ab);
  float P = 1.f;
  for (int k = 0; k < gcn; ++k) P *= q;

  size_t off = bn*DD + (size_t)l2*4;
  float4 t4 = ld4(tags + off), c1 = ld4(col1 + off), c2 = ld4(col2 + off);
  float4 tn  = mix4(ap, t4, xt);
  float4 c1f = mix4(s1, mix4(ap, c1, xl), ag);
  float4 c2f = mix4(s2, mix4(ap, c2, xr), ag);
  float4 u;
  u = mix4(aat, tn, bt);
  u.x = P*u.x + (1.f-P)*z4.x; u.y = P*u.y + (1.f-P)*z4.y;
  u.z = P*u.z + (1.f-P)*z4.z; u.w = P*u.w + (1.f-P)*z4.w;
  st4(o_t + off, u);
  u = mix4(aat, c1f, bl);
  u.x = P*u.x + (1.f-P)*z4.x; u.y = P*u.y + (1.f-P)*z4.y;
  u.z = P*u.z + (1.f-P)*z4.z; u.w = P*u.w + (1.f-P)*z4.w;
  st4(o_1 + off, u);
  u = mix4(aat, c2f, br);
  u.x = P*u.x + (1.f-P)*z4.x; u.y = P*u.y + (1.f-P)*z4.y;
  u.z = P*u.z + (1.f-P)*z4.z; u.w = P*u.w + (1.f-P)*z4.w;
  st4(o_2 + off, u);
}

__global__ __launch_bounds__(256) void kE(const float* __restrict__ tags,
                                          const float* __restrict__ col1,
                                          const float* __restrict__ col2,
                                          float* __restrict__ o_t,
                                          float* __restrict__ o_1,
                                          float* __restrict__ o_2,
                                          const float* __restrict__ f2cn,
                                          const float* __restrict__ csfn,
                                          const float* __restrict__ sc4,
                                          const float* __restrict__ vecs,
                                          const float* __restrict__ zv,
                                          const int* __restrict__ gcp,
                                          int B, int N, int CH){
  int blk = blockIdx.x, b = blk / CH, c = blk % CH;
  int rows = N / CH, n0 = c * rows;
  int t = threadIdx.x;
  int l2 = t & 31, r0 = t >> 5;    // 8 row-slots of 32 lanes
  size_t bN = (size_t)b * N;
  size_t BDv = (size_t)B * DD;

  const float* vb = vecs + (size_t)b*DD + (size_t)l2*4;
  float4 ag = ld4(vb + 1*BDv);
  float4 xt = ld4(vb + 4*BDv), xl = ld4(vb + 5*BDv), xr = ld4(vb + 6*BDv);
  float4 bt = ld4(vb + 7*BDv), bl = ld4(vb + 8*BDv), br = ld4(vb + 9*BDv);
  float4 z4 = ld4(zv + l2*4);
  int gcn = gcp[0];

  int r = r0;
  #pragma unroll 1
  for (; r + 8 < rows; r += 16){
    ke_row(bN + n0 + r,     l2, gcn, tags, col1, col2, f2cn, csfn, sc4,
           ag, xt, xl, xr, bt, bl, br, z4, o_t, o_1, o_2);
    ke_row(bN + n0 + r + 8, l2, gcn, tags, col1, col2, f2cn, csfn, sc4,
           ag, xt, xl, xr, bt, bl, br, z4, o_t, o_1, o_2);
  }
  if (r < rows)
    ke_row(bN + n0 + r, l2, gcn, tags, col1, col2, f2cn, csfn, sc4,
           ag, xt, xl, xr, bt, bl, br, z4, o_t, o_1, o_2);
}

extern "C" void kernel_launch(void* const* d_in, const int* in_sizes, int n_in,
                              void* d_out, int out_size, void* d_ws, size_t ws_size,
                              hipStream_t stream){
  const float* at   = (const float*)d_in[0];
  const float* addr = (const float*)d_in[1];
  const float* tags = (const float*)d_in[2];
  const float* col1 = (const float*)d_in[3];
  const float* col2 = (const float*)d_in[4];
  const float* zv   = (const float*)d_in[5];
  const int*   gc   = (const int*)d_in[6];

  int Dd = in_sizes[5];                 // 128
  int B  = in_sizes[0] / Dd;            // 32
  int N  = in_sizes[1] / in_sizes[0];   // 2048
  (void)Dd;

  size_t S  = (size_t)B * N;
  size_t BD = (size_t)B * DD;

  int CH = 32;
  while (CH > 1){
    size_t need = (7*S + 10*BD + (size_t)10*B*CH*DD) * sizeof(float) + 3*B*sizeof(unsigned);
    if (need <= ws_size && (N % CH) == 0) break;
    CH >>= 1;
  }

  // workspace layout (floats)
  float* w = (float*)d_ws;
  float* f2cn  = w;                                   // [S][2]: cs0, na
  float* csfn  = w + 2*S;                             // [S]
  float* sc4   = w + 3*S;                             // [S][4]: ap, csb, s1, s2
  float* vecs  = w + 7*S;                             // [10][B][DD]
  float* partA = vecs + 10*BD;                        // [2][B][CH][DD]
  float* partB = partA + (size_t)2*B*CH*DD;           // [5][B][CH][DD]
  float* partC = partB + (size_t)5*B*CH*DD;           // [3][B][CH][DD]
  unsigned* cnts = (unsigned*)(partC + (size_t)3*B*CH*DD);  // [3][B]
  unsigned* cntA = cnts, *cntB = cnts + B, *cntC = cnts + 2*B;

  float* o_t = (float*)d_out;
  float* o_1 = o_t + (size_t)B*N*DD;
  float* o_2 = o_1 + (size_t)B*N*DD;

  hipMemsetAsync(cnts, 0, 3*B*sizeof(unsigned), stream);

  dim3 blk(256);
  dim3 grid(B*CH);

  kA<<<grid, blk, 0, stream>>>(at, addr, col1, col2, f2cn, vecs, partA, cntA, B, N, CH);
  kB<<<grid, blk, 0, stream>>>(addr, tags, col1, col2, f2cn, csfn, vecs, partB, cntB, B, N, CH);
  kC<<<grid, blk, 0, stream>>>(addr, tags, col1, col2, f2cn, sc4, vecs, partC, cntC, B, N, CH);
  kE<<<grid, blk, 0, stream>>>(tags, col1, col2, o_t, o_1, o_2,
                               f2cn, csfn, sc4, vecs, zv, gc, B, N, CH);
}

// Round 7
// 126.360 us; speedup vs baseline: 3.6251x; 3.6251x over previous
//
#include <hip/hip_runtime.h>

#define EPSF 1e-8f
#define DD 128   // feature dim, fixed by problem

struct V2 { float4 A, B; };

// ---------- small helpers ----------
__device__ __forceinline__ float4 ld4(const float* p){ return *reinterpret_cast<const float4*>(p); }
__device__ __forceinline__ void st4(float* p, const float4& v){ *reinterpret_cast<float4*>(p) = v; }
__device__ __forceinline__ float dot4(const float4& a, const float4& b){
  return a.x*b.x + a.y*b.y + a.z*b.z + a.w*b.w;
}
__device__ __forceinline__ void fma4(float4& acc, const float4& a, float s){
  acc.x += a.x*s; acc.y += a.y*s; acc.z += a.z*s; acc.w += a.w*s;
}
__device__ __forceinline__ float4 mix4(float a, const float4& v, const float4& x){
  float4 r;
  r.x = (1.f-a)*v.x + a*x.x;
  r.y = (1.f-a)*v.y + a*x.y;
  r.z = (1.f-a)*v.z + a*x.z;
  r.w = (1.f-a)*v.w + a*x.w;
  return r;
}
__device__ __forceinline__ float red16(float v){
  v += __shfl_xor(v, 1);
  v += __shfl_xor(v, 2);
  v += __shfl_xor(v, 4);
  v += __shfl_xor(v, 8);
  return v;
}
__device__ __forceinline__ V2 ldrow(const float* p, size_t base, int l){
  V2 v; v.A = ld4(p + base + l*4); v.B = ld4(p + base + 64 + l*4); return v;
}
__device__ __forceinline__ float dotV(const V2& a, const V2& b){
  return dot4(a.A, b.A) + dot4(a.B, b.B);
}
// block-level reduction of 16 row-groups' (2x float4 per lane) partials into dst[0..127]
__device__ __forceinline__ void block_red16(float* red, int g, int l, int t,
                                            const V2& acc, float* dst){
  red[g*DD + l*4+0] = acc.A.x;
  red[g*DD + l*4+1] = acc.A.y;
  red[g*DD + l*4+2] = acc.A.z;
  red[g*DD + l*4+3] = acc.A.w;
  red[g*DD + 64 + l*4+0] = acc.B.x;
  red[g*DD + 64 + l*4+1] = acc.B.y;
  red[g*DD + 64 + l*4+2] = acc.B.z;
  red[g*DD + 64 + l*4+3] = acc.B.w;
  __syncthreads();
  if (t < DD){
    float s = 0.f;
    #pragma unroll
    for (int q = 0; q < 16; ++q) s += red[q*DD + t];
    dst[t] = s;
  }
  __syncthreads();
}

// ---------- per-row bodies ----------
__device__ __forceinline__ void ka_row(const V2& a, const V2& c1, const V2& c2,
                                       const V2& atv, float nat, int l,
                                       float* __restrict__ f2cn, size_t idx,
                                       V2& accF, V2& accA){
  float dp = red16(dotV(atv, a));
  float n2 = red16(dotV(a, a));
  float na = sqrtf(n2);
  float cs = dp / fmaxf(nat * na, EPSF);
  if (l == 0) *reinterpret_cast<float2*>(f2cn + 2*idx) = make_float2(cs, na);
  fma4(accF.A, c1.A, cs); fma4(accF.B, c1.B, cs);
  fma4(accA.A, c2.A, cs); fma4(accA.B, c2.B, cs);
}

__device__ __forceinline__ void kb_row(const V2& a, const V2& t4, const V2& c1, const V2& c2,
                                       const V2& fn, const V2& ag, float nfn, float nag,
                                       float na, int l, float* __restrict__ csfn, size_t idx,
                                       V2& accP, V2& accB, V2& accT, V2& accL, V2& accR){
  float dfn = red16(dotV(fn, a));
  float dag = red16(dotV(ag, a));
  float cf = dfn / fmaxf(nfn*na, EPSF);
  float ca = dag / fmaxf(nag*na, EPSF);
  if (l == 0) csfn[idx] = cf;
  fma4(accP.A, c1.A, cf); fma4(accP.B, c1.B, cf);
  fma4(accB.A, c2.A, cf); fma4(accB.B, c2.B, cf);
  fma4(accT.A, t4.A, ca); fma4(accT.B, t4.B, ca);
  fma4(accL.A, c1.A, ca); fma4(accL.B, c1.B, ca);
  fma4(accR.A, c2.A, ca); fma4(accR.B, c2.B, ca);
}

__device__ __forceinline__ void kc_row(const V2& a, const V2& t4, const V2& c1, const V2& c2,
                                       const V2& ag, const V2& pm, const V2& bd,
                                       const V2& xt, const V2& xl, const V2& xr,
                                       float npm, float nbd, float na, int l,
                                       float* __restrict__ sc4, size_t idx,
                                       V2& accT, V2& accL, V2& accR){
  float dp = red16(dotV(pm, a));
  float db = red16(dotV(bd, a));
  float csp = dp / fmaxf(npm*na, EPSF);
  float ap  = csp > EPSF ? csp : 0.f;
  float csb = db / fmaxf(nbd*na, EPSF);
  V2 tn { mix4(ap, t4.A, xt.A), mix4(ap, t4.B, xt.B) };
  V2 c1n{ mix4(ap, c1.A, xl.A), mix4(ap, c1.B, xl.B) };
  V2 c2n{ mix4(ap, c2.A, xr.A), mix4(ap, c2.B, xr.B) };
  float d1  = red16(dotV(pm, c1n));
  float n21 = red16(dotV(c1n, c1n));
  float d2  = red16(dotV(pm, c2n));
  float n22 = red16(dotV(c2n, c2n));
  float s1 = d1 / fmaxf(npm * sqrtf(n21), EPSF);
  float s2 = d2 / fmaxf(npm * sqrtf(n22), EPSF);
  V2 c1f{ mix4(s1, c1n.A, ag.A), mix4(s1, c1n.B, ag.B) };
  V2 c2f{ mix4(s2, c2n.A, ag.A), mix4(s2, c2n.B, ag.B) };
  if (l == 0) *reinterpret_cast<float4*>(sc4 + 4*idx) = make_float4(ap, csb, s1, s2);
  fma4(accT.A, tn.A,  csb); fma4(accT.B, tn.B,  csb);
  fma4(accL.A, c1f.A, csb); fma4(accL.B, c1f.B, csb);
  fma4(accR.A, c2f.A, csb); fma4(accR.B, c2f.B, csb);
}

// ---------- finalize: dst[v][b][d] = sum_c part[v][b][c][d]  (tiny launch) ----------
__global__ void kFin(const float* __restrict__ part, float* __restrict__ dst,
                     int nvec, int B, int CH){
  int i = blockIdx.x*blockDim.x + threadIdx.x;
  int total = nvec * B * DD;
  if (i >= total) return;
  int d = i & (DD-1);
  int vb = i >> 7;                 // vec*B + b
  const float* p = part + ((size_t)vb*CH)*DD + d;
  float s = 0.f;
  for (int c = 0; c < CH; ++c) s += p[(size_t)c*DD];
  dst[i] = s;
}

// ---------- kernel A ----------
__global__ __launch_bounds__(256) void kA(const float* __restrict__ at,
                                          const float* __restrict__ addr,
                                          const float* __restrict__ col1,
                                          const float* __restrict__ col2,
                                          float* __restrict__ f2cn,
                                          float* __restrict__ partA,
                                          int B, int N, int CH){
  __shared__ float red[16*DD];
  int blk = blockIdx.x, b = blk / CH, c = blk % CH;
  int rows = N / CH, n0 = c * rows;
  int t = threadIdx.x, g = t >> 4, l = t & 15;
  size_t bN = (size_t)b * N;

  const float* atp = at + (size_t)b*DD;
  V2 atv{ ld4(atp + l*4), ld4(atp + 64 + l*4) };
  float nat = sqrtf(red16(dotV(atv, atv)));

  V2 zz{ make_float4(0,0,0,0), make_float4(0,0,0,0) };
  V2 accF = zz, accA = zz;
  int r = g;
  #pragma unroll 1
  for (; r + 16 < rows; r += 32){
    size_t n1 = (size_t)n0 + r, n2 = (size_t)n0 + r + 16;
    size_t b1 = (bN + n1)*DD, b2 = (bN + n2)*DD;
    V2 a1 = ldrow(addr, b1, l), a2 = ldrow(addr, b2, l);
    V2 x1 = ldrow(col1, b1, l), x2 = ldrow(col1, b2, l);
    V2 y1 = ldrow(col2, b1, l), y2 = ldrow(col2, b2, l);
    ka_row(a1, x1, y1, atv, nat, l, f2cn, bN + n1, accF, accA);
    ka_row(a2, x2, y2, atv, nat, l, f2cn, bN + n2, accF, accA);
  }
  if (r < rows){
    size_t n1 = (size_t)n0 + r, b1 = (bN + n1)*DD;
    V2 a1 = ldrow(addr, b1, l), x1 = ldrow(col1, b1, l), y1 = ldrow(col2, b1, l);
    ka_row(a1, x1, y1, atv, nat, l, f2cn, bN + n1, accF, accA);
  }
  block_red16(red, g, l, t, accF, partA + ((size_t)(0*B + b)*CH + c)*DD);
  block_red16(red, g, l, t, accA, partA + ((size_t)(1*B + b)*CH + c)*DD);
}

// ---------- kernel B ----------
__global__ __launch_bounds__(256) void kB(const float* __restrict__ addr,
                                          const float* __restrict__ tags,
                                          const float* __restrict__ col1,
                                          const float* __restrict__ col2,
                                          const float* __restrict__ f2cn,
                                          float* __restrict__ csfn,
                                          const float* __restrict__ vecs,
                                          float* __restrict__ partB,
                                          int B, int N, int CH){
  __shared__ float red[16*DD];
  int blk = blockIdx.x, b = blk / CH, c = blk % CH;
  int rows = N / CH, n0 = c * rows;
  int t = threadIdx.x, g = t >> 4, l = t & 15;
  size_t bN = (size_t)b * N;
  size_t BDv = (size_t)B * DD;

  const float* fnp = vecs + (size_t)b*DD;
  const float* agp = vecs + BDv + (size_t)b*DD;
  V2 fn{ ld4(fnp + l*4), ld4(fnp + 64 + l*4) };
  V2 ag{ ld4(agp + l*4), ld4(agp + 64 + l*4) };
  float nfn = sqrtf(red16(dotV(fn, fn)));
  float nag = sqrtf(red16(dotV(ag, ag)));

  V2 zz{ make_float4(0,0,0,0), make_float4(0,0,0,0) };
  V2 accP = zz, accB = zz, accT = zz, accL = zz, accR = zz;
  int r = g;
  #pragma unroll 1
  for (; r + 16 < rows; r += 32){
    size_t n1 = (size_t)n0 + r, n2 = (size_t)n0 + r + 16;
    size_t b1 = (bN + n1)*DD, b2 = (bN + n2)*DD;
    V2 a1 = ldrow(addr, b1, l), a2 = ldrow(addr, b2, l);
    V2 t1 = ldrow(tags, b1, l), t2 = ldrow(tags, b2, l);
    V2 x1 = ldrow(col1, b1, l), x2 = ldrow(col1, b2, l);
    V2 y1 = ldrow(col2, b1, l), y2 = ldrow(col2, b2, l);
    float na1 = f2cn[2*(bN + n1) + 1], na2 = f2cn[2*(bN + n2) + 1];
    kb_row(a1, t1, x1, y1, fn, ag, nfn, nag, na1, l, csfn, bN + n1, accP, accB, accT, accL, accR);
    kb_row(a2, t2, x2, y2, fn, ag, nfn, nag, na2, l, csfn, bN + n2, accP, accB, accT, accL, accR);
  }
  if (r < rows){
    size_t n1 = (size_t)n0 + r, b1 = (bN + n1)*DD;
    V2 a1 = ldrow(addr, b1, l), t1 = ldrow(tags, b1, l);
    V2 x1 = ldrow(col1, b1, l), y1 = ldrow(col2, b1, l);
    float na1 = f2cn[2*(bN + n1) + 1];
    kb_row(a1, t1, x1, y1, fn, ag, nfn, nag, na1, l, csfn, bN + n1, accP, accB, accT, accL, accR);
  }
  block_red16(red, g, l, t, accP, partB + ((size_t)(0*B + b)*CH + c)*DD);
  block_red16(red, g, l, t, accB, partB + ((size_t)(1*B + b)*CH + c)*DD);
  block_red16(red, g, l, t, accT, partB + ((size_t)(2*B + b)*CH + c)*DD);
  block_red16(red, g, l, t, accL, partB + ((size_t)(3*B + b)*CH + c)*DD);
  block_red16(red, g, l, t, accR, partB + ((size_t)(4*B + b)*CH + c)*DD);
}

// ---------- kernel C ----------
__global__ __launch_bounds__(256) void kC(const float* __restrict__ addr,
                                          const float* __restrict__ tags,
                                          const float* __restrict__ col1,
                                          const float* __restrict__ col2,
                                          const float* __restrict__ f2cn,
                                          float* __restrict__ sc4,
                                          const float* __restrict__ vecs,
                                          float* __restrict__ partC,
                                          int B, int N, int CH){
  __shared__ float red[16*DD];
  int blk = blockIdx.x, b = blk / CH, c = blk % CH;
  int rows = N / CH, n0 = c * rows;
  int t = threadIdx.x, g = t >> 4, l = t & 15;
  size_t bN = (size_t)b * N;
  size_t BDv = (size_t)B * DD;

  const float* vp = vecs + (size_t)b*DD;
  V2 ag{ ld4(vp + 1*BDv + l*4), ld4(vp + 1*BDv + 64 + l*4) };
  V2 pm{ ld4(vp + 2*BDv + l*4), ld4(vp + 2*BDv + 64 + l*4) };
  V2 bd{ ld4(vp + 3*BDv + l*4), ld4(vp + 3*BDv + 64 + l*4) };
  V2 xt{ ld4(vp + 4*BDv + l*4), ld4(vp + 4*BDv + 64 + l*4) };
  V2 xl{ ld4(vp + 5*BDv + l*4), ld4(vp + 5*BDv + 64 + l*4) };
  V2 xr{ ld4(vp + 6*BDv + l*4), ld4(vp + 6*BDv + 64 + l*4) };
  float npm = sqrtf(red16(dotV(pm, pm)));
  float nbd = sqrtf(red16(dotV(bd, bd)));

  V2 zz{ make_float4(0,0,0,0), make_float4(0,0,0,0) };
  V2 accT = zz, accL = zz, accR = zz;
  int r = g;
  #pragma unroll 1
  for (; r + 16 < rows; r += 32){
    size_t n1 = (size_t)n0 + r, n2 = (size_t)n0 + r + 16;
    size_t b1 = (bN + n1)*DD, b2 = (bN + n2)*DD;
    V2 a1 = ldrow(addr, b1, l), a2 = ldrow(addr, b2, l);
    V2 t1 = ldrow(tags, b1, l), t2 = ldrow(tags, b2, l);
    V2 x1 = ldrow(col1, b1, l), x2 = ldrow(col1, b2, l);
    V2 y1 = ldrow(col2, b1, l), y2 = ldrow(col2, b2, l);
    float na1 = f2cn[2*(bN + n1) + 1], na2 = f2cn[2*(bN + n2) + 1];
    kc_row(a1, t1, x1, y1, ag, pm, bd, xt, xl, xr, npm, nbd, na1, l, sc4, bN + n1, accT, accL, accR);
    kc_row(a2, t2, x2, y2, ag, pm, bd, xt, xl, xr, npm, nbd, na2, l, sc4, bN + n2, accT, accL, accR);
  }
  if (r < rows){
    size_t n1 = (size_t)n0 + r, b1 = (bN + n1)*DD;
    V2 a1 = ldrow(addr, b1, l), t1 = ldrow(tags, b1, l);
    V2 x1 = ldrow(col1, b1, l), y1 = ldrow(col2, b1, l);
    float na1 = f2cn[2*(bN + n1) + 1];
    kc_row(a1, t1, x1, y1, ag, pm, bd, xt, xl, xr, npm, nbd, na1, l, sc4, bN + n1, accT, accL, accR);
  }
  block_red16(red, g, l, t, accT, partC + ((size_t)(0*B + b)*CH + c)*DD);
  block_red16(red, g, l, t, accL, partC + ((size_t)(1*B + b)*CH + c)*DD);
  block_red16(red, g, l, t, accR, partC + ((size_t)(2*B + b)*CH + c)*DD);
}

// ---------- kernel E: streaming final pass ----------
__device__ __forceinline__ void ke_row(size_t bn, int l2, int gcn,
    const float* __restrict__ tags, const float* __restrict__ col1, const float* __restrict__ col2,
    const float* __restrict__ f2cn, const float* __restrict__ csfn, const float* __restrict__ sc4,
    const float4& ag, const float4& xt, const float4& xl, const float4& xr,
    const float4& bt, const float4& bl, const float4& br, const float4& z4,
    float* __restrict__ o_t, float* __restrict__ o_1, float* __restrict__ o_2){
  float4 sc = ld4(sc4 + 4*bn);                                   // ap, csb, s1, s2
  float2 cn = *reinterpret_cast<const float2*>(f2cn + 2*bn);     // cs0, na
  float cf = csfn[bn];
  float ap = sc.x, cb = sc.y, s1 = sc.z, s2 = sc.w, c0 = cn.x;
  float aat = c0 > EPSF ? c0 : 0.f;
  float af  = cf > EPSF ? cf : 0.f;
  float ab  = cb > EPSF ? cb : 0.f;
  float q = (1.f-af)*(1.f-ap)*(1.f-ab);
  float P = 1.f;
  for (int k = 0; k < gcn; ++k) P *= q;

  size_t off = bn*DD + (size_t)l2*4;
  float4 t4 = ld4(tags + off), c1 = ld4(col1 + off), c2 = ld4(col2 + off);
  float4 tn  = mix4(ap, t4, xt);
  float4 c1f = mix4(s1, mix4(ap, c1, xl), ag);
  float4 c2f = mix4(s2, mix4(ap, c2, xr), ag);
  float4 u;
  u = mix4(aat, tn, bt);
  u.x = P*u.x + (1.f-P)*z4.x; u.y = P*u.y + (1.f-P)*z4.y;
  u.z = P*u.z + (1.f-P)*z4.z; u.w = P*u.w + (1.f-P)*z4.w;
  st4(o_t + off, u);
  u = mix4(aat, c1f, bl);
  u.x = P*u.x + (1.f-P)*z4.x; u.y = P*u.y + (1.f-P)*z4.y;
  u.z = P*u.z + (1.f-P)*z4.z; u.w = P*u.w + (1.f-P)*z4.w;
  st4(o_1 + off, u);
  u = mix4(aat, c2f, br);
  u.x = P*u.x + (1.f-P)*z4.x; u.y = P*u.y + (1.f-P)*z4.y;
  u.z = P*u.z + (1.f-P)*z4.z; u.w = P*u.w + (1.f-P)*z4.w;
  st4(o_2 + off, u);
}

__global__ __launch_bounds__(256) void kE(const float* __restrict__ tags,
                                          const float* __restrict__ col1,
                                          const float* __restrict__ col2,
                                          float* __restrict__ o_t,
                                          float* __restrict__ o_1,
                                          float* __restrict__ o_2,
                                          const float* __restrict__ f2cn,
                                          const float* __restrict__ csfn,
                                          const float* __restrict__ sc4,
                                          const float* __restrict__ vecs,
                                          const float* __restrict__ zv,
                                          const int* __restrict__ gcp,
                                          int B, int N, int CH){
  int blk = blockIdx.x, b = blk / CH, c = blk % CH;
  int rows = N / CH, n0 = c * rows;
  int t = threadIdx.x;
  int l2 = t & 31, r0 = t >> 5;    // 8 row-slots of 32 lanes
  size_t bN = (size_t)b * N;
  size_t BDv = (size_t)B * DD;

  const float* vb = vecs + (size_t)b*DD + (size_t)l2*4;
  float4 ag = ld4(vb + 1*BDv);
  float4 xt = ld4(vb + 4*BDv), xl = ld4(vb + 5*BDv), xr = ld4(vb + 6*BDv);
  float4 bt = ld4(vb + 7*BDv), bl = ld4(vb + 8*BDv), br = ld4(vb + 9*BDv);
  float4 z4 = ld4(zv + l2*4);
  int gcn = gcp[0];

  int r = r0;
  #pragma unroll 1
  for (; r + 8 < rows; r += 16){
    ke_row(bN + n0 + r,     l2, gcn, tags, col1, col2, f2cn, csfn, sc4,
           ag, xt, xl, xr, bt, bl, br, z4, o_t, o_1, o_2);
    ke_row(bN + n0 + r + 8, l2, gcn, tags, col1, col2, f2cn, csfn, sc4,
           ag, xt, xl, xr, bt, bl, br, z4, o_t, o_1, o_2);
  }
  if (r < rows)
    ke_row(bN + n0 + r, l2, gcn, tags, col1, col2, f2cn, csfn, sc4,
           ag, xt, xl, xr, bt, bl, br, z4, o_t, o_1, o_2);
}

extern "C" void kernel_launch(void* const* d_in, const int* in_sizes, int n_in,
                              void* d_out, int out_size, void* d_ws, size_t ws_size,
                              hipStream_t stream){
  const float* at   = (const float*)d_in[0];
  const float* addr = (const float*)d_in[1];
  const float* tags = (const float*)d_in[2];
  const float* col1 = (const float*)d_in[3];
  const float* col2 = (const float*)d_in[4];
  const float* zv   = (const float*)d_in[5];
  const int*   gc   = (const int*)d_in[6];

  int Dd = in_sizes[5];                 // 128
  int B  = in_sizes[0] / Dd;            // 32
  int N  = in_sizes[1] / in_sizes[0];   // 2048
  (void)Dd;

  size_t S  = (size_t)B * N;
  size_t BD = (size_t)B * DD;

  int CH = 32;
  while (CH > 1){
    size_t need = (7*S + 10*BD + (size_t)10*B*CH*DD) * sizeof(float);
    if (need <= ws_size && (N % CH) == 0) break;
    CH >>= 1;
  }

  // workspace layout (floats)
  float* w = (float*)d_ws;
  float* f2cn  = w;                                   // [S][2]: cs0, na
  float* csfn  = w + 2*S;                             // [S]
  float* sc4   = w + 3*S;                             // [S][4]: ap, csb, s1, s2
  float* vecs  = w + 7*S;                             // [10][B][DD]
  float* partA = vecs + 10*BD;                        // [2][B][CH][DD]
  float* partB = partA + (size_t)2*B*CH*DD;           // [5][B][CH][DD]
  float* partC = partB + (size_t)5*B*CH*DD;           // [3][B][CH][DD]

  float* o_t = (float*)d_out;
  float* o_1 = o_t + (size_t)B*N*DD;
  float* o_2 = o_1 + (size_t)B*N*DD;

  dim3 blk(256);
  dim3 grid(B*CH);

  kA<<<grid, blk, 0, stream>>>(at, addr, col1, col2, f2cn, partA, B, N, CH);
  kFin<<<(2*B*DD + 255)/256, 256, 0, stream>>>(partA, vecs + 0*BD, 2, B, CH);
  kB<<<grid, blk, 0, stream>>>(addr, tags, col1, col2, f2cn, csfn, vecs, partB, B, N, CH);
  kFin<<<(5*B*DD + 255)/256, 256, 0, stream>>>(partB, vecs + 2*BD, 5, B, CH);
  kC<<<grid, blk, 0, stream>>>(addr, tags, col1, col2, f2cn, sc4, vecs, partC, B, N, CH);
  kFin<<<(3*B*DD + 255)/256, 256, 0, stream>>>(partC, vecs + 7*BD, 3, B, CH);
  kE<<<grid, blk, 0, stream>>>(tags, col1, col2, o_t, o_1, o_2,
                               f2cn, csfn, sc4, vecs, zv, gc, B, N, CH);
}